// Round 6
// baseline (50.306 us; speedup 1.0000x reference)
//
#include <hip/hip_runtime.h>
#include <hip/hip_cooperative_groups.h>
#include <math.h>

namespace cg = cooperative_groups;

#define EPS 1e-5f

// Single cooperative launch. Grid = 256 blocks x 256 threads (1 block/CU,
// 86KB LDS -> guaranteed co-resident; cooperative launch validates this).
// Blocks 0..63 build one row of the 64-token table (the whole net up to `hs`
// depends only on the token id); grid.sync(); then every block runs the
// per-batch-row histogram ranking + attention epilogue.
// ws float layout: [0,4096) HS table; [4096,4160) gate scores.
__global__ __launch_bounds__(256, 1) void slot_coop(
    const int* __restrict__ seq,
    const float* __restrict__ embed,
    const float* __restrict__ W1, const float* __restrict__ b1,
    const float* __restrict__ W2, const float* __restrict__ b2,
    const float* __restrict__ gamma, const float* __restrict__ beta,
    const float* __restrict__ Wq, const float* __restrict__ bq,
    const float* __restrict__ Wo, const float* __restrict__ bo,
    float* __restrict__ wsf,
    float* __restrict__ out)
{
    __shared__ float HS[64][65];   // pad 65: row+col patterns conflict-free
    __shared__ int   hist[4][64];
    __shared__ float e[64];
    __shared__ float Up[2][128];
    __shared__ float Ux[128];
    __shared__ float Hp[4][64];
    __shared__ float qv[64];
    __shared__ int   tlast_s;

    const int tid = threadIdx.x;
    const int wv  = tid >> 6;
    const int ln  = tid & 63;
    const int b   = blockIdx.x;
    const int* row = seq + b * 4096;

    hist[wv][ln] = 0;

    // Issue own-row seq loads immediately (latency hides under table build).
    int4 s0 = reinterpret_cast<const int4*>(row)[tid];
    int4 s1 = reinterpret_cast<const int4*>(row)[tid + 256];
    int4 s2 = reinterpret_cast<const int4*>(row)[tid + 512];
    int4 s3 = reinterpret_cast<const int4*>(row)[tid + 768];

    // Register prefetch: wave0 = Wo column + bo; wave1 = Wq column + bq.
    float wcol[64];
    float bias = 0.f;
    if (wv == 0) {
        #pragma unroll
        for (int k = 0; k < 64; ++k) wcol[k] = Wo[k * 64 + ln];
        bias = bo[ln];
    } else if (wv == 1) {
        #pragma unroll
        for (int k = 0; k < 64; ++k) wcol[k] = Wq[k * 64 + ln];
        bias = bq[ln];
    }

    // ---------------- producers: blocks 0..63 build table row b ----------
    if (b < 64) {
        if (tid < 64) e[tid] = embed[b * 64 + tid];
        __syncthreads();
        {   // U = relu(e@W1+b1): thread (j=tid&127, half h); W1 from L2
            int j = tid & 127, h = tid >> 7, k0 = h << 5;
            float acc = 0.f;
            #pragma unroll
            for (int k = 0; k < 32; ++k)
                acc = fmaf(e[k0 + k], W1[(k0 + k) * 128 + j], acc);
            Up[h][j] = acc;
        }
        __syncthreads();
        if (tid < 128) Ux[tid] = fmaxf(b1[tid] + Up[0][tid] + Up[1][tid], 0.f);
        __syncthreads();
        {   // H = e + U@W2 + b2: thread (j=tid&63, quarter qd); W2 from L2
            int j = tid & 63, qd = tid >> 6, k0 = qd << 5;
            float acc = 0.f;
            #pragma unroll
            for (int k = 0; k < 32; ++k)
                acc = fmaf(Ux[k0 + k], W2[(k0 + k) * 64 + j], acc);
            Hp[qd][j] = acc;
        }
        __syncthreads();
        if (tid < 64) {   // LN + gamma/beta + gate norm
            float h = e[tid] + b2[tid] + Hp[0][tid] + Hp[1][tid] + Hp[2][tid] + Hp[3][tid];
            float s = h;
            #pragma unroll
            for (int off = 1; off < 64; off <<= 1) s += __shfl_xor(s, off);
            float mu = s * (1.f / 64.f);
            float d = h - mu;
            float v = d * d;
            #pragma unroll
            for (int off = 1; off < 64; off <<= 1) v += __shfl_xor(v, off);
            float rstd = rsqrtf(v * (1.f / 64.f) + EPS);
            float hs = d * rstd * gamma[tid] + beta[tid];
            wsf[b * 64 + tid] = hs;
            float ss = hs * hs;
            #pragma unroll
            for (int off = 1; off < 64; off <<= 1) ss += __shfl_xor(ss, off);
            if (tid == 0) wsf[4096 + b] = sqrtf(ss);
        }
        __threadfence();   // agent release: table visible to all XCDs
    }

    // ---------------- grid-wide barrier (release+acquire) -----------------
    cg::this_grid().sync();

    // ---------------- all blocks: LDS histogram of own row ----------------
    atomicAdd(&hist[wv][s0.x], 1); atomicAdd(&hist[wv][s0.y], 1);
    atomicAdd(&hist[wv][s0.z], 1); atomicAdd(&hist[wv][s0.w], 1);
    atomicAdd(&hist[wv][s1.x], 1); atomicAdd(&hist[wv][s1.y], 1);
    atomicAdd(&hist[wv][s1.z], 1); atomicAdd(&hist[wv][s1.w], 1);
    atomicAdd(&hist[wv][s2.x], 1); atomicAdd(&hist[wv][s2.y], 1);
    atomicAdd(&hist[wv][s2.z], 1); atomicAdd(&hist[wv][s2.w], 1);
    atomicAdd(&hist[wv][s3.x], 1);                  // pos 4092 included
    if (tid != 255) {
        atomicAdd(&hist[wv][s3.y], 1);
        atomicAdd(&hist[wv][s3.z], 1);
        atomicAdd(&hist[wv][s3.w], 1);
    } else {
        tlast_s = s3.w;                             // pos 4095
    }

    // Stage HS table (16KB, L2-resident) + score.
    #pragma unroll
    for (int i = 0; i < 4; ++i) {
        int idx4 = tid + 256 * i;
        float4 v = reinterpret_cast<const float4*>(wsf)[idx4];
        int t = idx4 >> 4, j0 = (idx4 & 15) << 2;
        HS[t][j0] = v.x; HS[t][j0+1] = v.y; HS[t][j0+2] = v.z; HS[t][j0+3] = v.w;
    }
    float sc_r = (wv == 0) ? wsf[4096 + ln] : 0.f;
    __syncthreads();   // hist + tlast + HS complete

    // Phase 1: wave0 -> slot counts; wave1 -> q = HS[tlast]@Wq + bq.
    int cnt_i = 0;
    if (wv == 0) {
        int h = hist[0][ln] + hist[1][ln] + hist[2][ln] + hist[3][ln];
        float my = sc_r;
        int S = 0;   // occurrences of tokens ranked strictly before ln
        for (int t2 = 0; t2 < 64; ++t2) {
            float s2 = __shfl(sc_r, t2);
            int   h2 = __shfl(h, t2);
            bool before = (s2 > my) || (s2 == my && t2 < ln);
            if (before) S += h2;
        }
        int rem = 64 - S;
        rem = rem < 0 ? 0 : rem;
        cnt_i = h < rem ? h : rem;
    } else if (wv == 1) {
        int tl = tlast_s;
        float acc = bias;
        #pragma unroll
        for (int k = 0; k < 64; ++k)
            acc = fmaf(HS[tl][k], wcol[k], acc);    // HS broadcast, wcol regs
        qv[ln] = acc;
    }
    __syncthreads();

    // Phase 2: wave0: logits -> softmax(w/ multiplicity) -> ctx -> out.
    if (wv == 0) {
        float acc = 0.f;
        #pragma unroll 8
        for (int k = 0; k < 64; ++k)
            acc = fmaf(qv[k], HS[ln][k], acc);
        float logit = acc * 0.125f;                 // / sqrt(64)
        float lm = (cnt_i > 0) ? logit : -1e30f;
        #pragma unroll
        for (int off = 1; off < 64; off <<= 1) lm = fmaxf(lm, __shfl_xor(lm, off));
        float wvv = (cnt_i > 0) ? (float)cnt_i * __expf(logit - lm) : 0.f;
        float z = wvv;
        #pragma unroll
        for (int off = 1; off < 64; off <<= 1) z += __shfl_xor(z, off);
        float w_reg = wvv / z;                      // lane t holds weight_t

        float cacc = 0.f;                           // ctx[ln]
        #pragma unroll 8
        for (int t2 = 0; t2 < 64; ++t2)
            cacc = fmaf(__shfl(w_reg, t2), HS[t2][ln], cacc);

        float oacc = bias;                          // out[ln]
        #pragma unroll
        for (int k = 0; k < 64; ++k)
            oacc = fmaf(__shfl(cacc, k), wcol[k], oacc);
        out[b * 64 + ln] = oacc;
    }
}

extern "C" void kernel_launch(void* const* d_in, const int* in_sizes, int n_in,
                              void* d_out, int out_size, void* d_ws, size_t ws_size,
                              hipStream_t stream) {
    const int*   seq   = (const int*)d_in[0];
    const float* embed = (const float*)d_in[1];
    const float* W1    = (const float*)d_in[2];
    const float* b1    = (const float*)d_in[3];
    const float* W2    = (const float*)d_in[4];
    const float* b2    = (const float*)d_in[5];
    const float* gamma = (const float*)d_in[6];
    const float* beta  = (const float*)d_in[7];
    const float* Wq    = (const float*)d_in[8];
    const float* bq    = (const float*)d_in[9];
    const float* Wo    = (const float*)d_in[10];
    const float* bo    = (const float*)d_in[11];
    float* out = (float*)d_out;
    float* wsf = (float*)d_ws;
    (void)in_sizes; (void)n_in; (void)out_size; (void)ws_size;

    void* args[] = { (void*)&seq, (void*)&embed, (void*)&W1, (void*)&b1,
                     (void*)&W2, (void*)&b2, (void*)&gamma, (void*)&beta,
                     (void*)&Wq, (void*)&bq, (void*)&Wo, (void*)&bo,
                     (void*)&wsf, (void*)&out };
    hipLaunchCooperativeKernel((const void*)slot_coop, dim3(256), dim3(256),
                               args, 0, stream);
}

// Round 7
// 25.604 us; speedup vs baseline: 1.9648x; 1.9648x over previous
//
#include <hip/hip_runtime.h>
#include <math.h>

#define EPS 1e-5f

// Single plain launch, 256 blocks x 512 threads (8 waves), 1 block/CU.
// Every block redundantly rebuilds the 64-token table (the whole net up to
// `hs` depends only on token id; VALU floor ~3.4us is wall-clock free at
// grid==CU count), histograms its own batch row, and runs the epilogue.
// Layouts: activations transposed in LDS (lane-indexed, conflict-free),
// weights row-major (wave-uniform broadcast reads, free).
__global__ __launch_bounds__(512, 1) void slot_single(
    const int* __restrict__ seq,
    const float* __restrict__ embed,
    const float* __restrict__ W1, const float* __restrict__ b1,
    const float* __restrict__ W2, const float* __restrict__ b2,
    const float* __restrict__ gamma, const float* __restrict__ beta,
    const float* __restrict__ Wq, const float* __restrict__ bq,
    const float* __restrict__ Wo, const float* __restrict__ bo,
    float* __restrict__ out)
{
    __shared__ float Et[64][65];    // Et[k][t] = embed[t][k]
    __shared__ float W1s[64][128];  // row-major: broadcast reads
    __shared__ float W2s[128][64];
    __shared__ float Ut[128][65];   // Ut[k][t] = relu(e@W1+b1)[t][k]
    __shared__ float HS[64][65];    // layernormed table, row-major
    __shared__ float Pp[8][64];     // per-wave LN partials
    __shared__ float qv[64];
    __shared__ int   hist[8][64];
    __shared__ int   tlast_s;

    const int tid = threadIdx.x;
    const int wv  = tid >> 6;       // 0..7
    const int ln  = tid & 63;       // lane
    const int b   = blockIdx.x;
    const int* row = seq + b * 4096;

    hist[wv][ln] = 0;

    // Own-row seq loads (latency hides under the table build).
    int4 sA = reinterpret_cast<const int4*>(row)[tid];
    int4 sB = reinterpret_cast<const int4*>(row)[tid + 512];

    // Register prefetch: wave0 = Wo column + bo; wave1 = Wq column + bq.
    float wcol[64];
    float bias = 0.f;
    if (wv == 0) {
        #pragma unroll
        for (int k = 0; k < 64; ++k) wcol[k] = Wo[k * 64 + ln];
        bias = bo[ln];
    } else if (wv == 1) {
        #pragma unroll
        for (int k = 0; k < 64; ++k) wcol[k] = Wq[k * 64 + ln];
        bias = bq[ln];
    }

    // Stage W1 (32KB) + W2 (32KB) row-major, embed transposed (16KB).
    #pragma unroll
    for (int i = 0; i < 4; ++i) {
        reinterpret_cast<float4*>(&W1s[0][0])[tid + 512 * i] =
            reinterpret_cast<const float4*>(W1)[tid + 512 * i];
        reinterpret_cast<float4*>(&W2s[0][0])[tid + 512 * i] =
            reinterpret_cast<const float4*>(W2)[tid + 512 * i];
    }
    #pragma unroll
    for (int j = 0; j < 2; ++j) {
        int f4 = tid + 512 * j;                  // 1024 float4 of embed
        float4 v = reinterpret_cast<const float4*>(embed)[f4];
        int t = f4 >> 4, k0 = (f4 & 15) << 2;
        Et[k0][t] = v.x; Et[k0+1][t] = v.y; Et[k0+2][t] = v.z; Et[k0+3][t] = v.w;
    }
    __syncthreads();

    // ---- U = relu(e@W1 + b1): thread (t=ln, cols 16*wv..16*wv+15) ----
    {
        const int c0 = wv << 4;
        float acc[16];
        #pragma unroll
        for (int m = 0; m < 4; ++m) {
            float4 bb = *reinterpret_cast<const float4*>(&b1[c0 + 4*m]);
            acc[4*m] = bb.x; acc[4*m+1] = bb.y; acc[4*m+2] = bb.z; acc[4*m+3] = bb.w;
        }
        for (int k = 0; k < 64; ++k) {
            float e = Et[k][ln];                             // lane-indexed, CF
            #pragma unroll
            for (int m = 0; m < 4; ++m) {
                float4 w = *reinterpret_cast<const float4*>(&W1s[k][c0 + 4*m]);
                acc[4*m]   = fmaf(e, w.x, acc[4*m]);
                acc[4*m+1] = fmaf(e, w.y, acc[4*m+1]);
                acc[4*m+2] = fmaf(e, w.z, acc[4*m+2]);
                acc[4*m+3] = fmaf(e, w.w, acc[4*m+3]);
            }
        }
        #pragma unroll
        for (int i = 0; i < 16; ++i)
            Ut[c0 + i][ln] = fmaxf(acc[i], 0.f);             // lanes consecutive
    }

    // Histogram own row into per-wave sub-hists (overlaps U's VALU via sched).
    atomicAdd(&hist[wv][sA.x], 1); atomicAdd(&hist[wv][sA.y], 1);
    atomicAdd(&hist[wv][sA.z], 1); atomicAdd(&hist[wv][sA.w], 1);
    atomicAdd(&hist[wv][sB.x], 1);                           // pos 4092 incl.
    if (tid != 511) {
        atomicAdd(&hist[wv][sB.y], 1);
        atomicAdd(&hist[wv][sB.z], 1);
        atomicAdd(&hist[wv][sB.w], 1);
    } else {
        tlast_s = sB.w;                                      // pos 4095
    }
    __syncthreads();

    // ---- H = e + U@W2 + b2: thread (t=ln, cols 8*wv..8*wv+7), fused LN ----
    float hacc[8];
    {
        const int j0 = wv << 3;
        #pragma unroll
        for (int m = 0; m < 2; ++m) {
            float4 bb = *reinterpret_cast<const float4*>(&b2[j0 + 4*m]);
            hacc[4*m] = bb.x; hacc[4*m+1] = bb.y; hacc[4*m+2] = bb.z; hacc[4*m+3] = bb.w;
        }
        for (int k = 0; k < 128; ++k) {
            float u = Ut[k][ln];                             // lane-indexed, CF
            #pragma unroll
            for (int m = 0; m < 2; ++m) {
                float4 w = *reinterpret_cast<const float4*>(&W2s[k][j0 + 4*m]);
                hacc[4*m]   = fmaf(u, w.x, hacc[4*m]);
                hacc[4*m+1] = fmaf(u, w.y, hacc[4*m+1]);
                hacc[4*m+2] = fmaf(u, w.z, hacc[4*m+2]);
                hacc[4*m+3] = fmaf(u, w.w, hacc[4*m+3]);
            }
        }
        #pragma unroll
        for (int i = 0; i < 8; ++i) hacc[i] += Et[j0 + i][ln];   // residual

        float s8 = 0.f;
        #pragma unroll
        for (int i = 0; i < 8; ++i) s8 += hacc[i];
        Pp[wv][ln] = s8;
    }
    __syncthreads();

    float mu;
    {
        float s = 0.f;
        #pragma unroll
        for (int w = 0; w < 8; ++w) s += Pp[w][ln];
        mu = s * (1.f / 64.f);
        float v8 = 0.f;
        #pragma unroll
        for (int i = 0; i < 8; ++i) { float d = hacc[i] - mu; v8 = fmaf(d, d, v8); }
        __syncthreads();                 // all sum-reads done before overwrite
        Pp[wv][ln] = v8;
    }
    __syncthreads();
    {
        const int j0 = wv << 3;
        float v = 0.f;
        #pragma unroll
        for (int w = 0; w < 8; ++w) v += Pp[w][ln];
        float rstd = rsqrtf(v * (1.f / 64.f) + EPS);
        float4 g0 = *reinterpret_cast<const float4*>(&gamma[j0]);
        float4 g1 = *reinterpret_cast<const float4*>(&gamma[j0 + 4]);
        float4 be0 = *reinterpret_cast<const float4*>(&beta[j0]);
        float4 be1 = *reinterpret_cast<const float4*>(&beta[j0 + 4]);
        float gg[8] = {g0.x,g0.y,g0.z,g0.w,g1.x,g1.y,g1.z,g1.w};
        float bb[8] = {be0.x,be0.y,be0.z,be0.w,be1.x,be1.y,be1.z,be1.w};
        #pragma unroll
        for (int i = 0; i < 8; ++i)
            HS[ln][j0 + i] = (hacc[i] - mu) * rstd * gg[i] + bb[i];
    }
    __syncthreads();   // HS complete; hist complete long ago

    // ---- Phase 1: wave0 -> scores+counts; wave1 -> q = HS[tlast]@Wq+bq ----
    int cnt_i = 0;
    if (wv == 0) {
        int h = 0;
        #pragma unroll
        for (int w = 0; w < 8; ++w) h += hist[w][ln];
        float ss = 0.f;
        #pragma unroll 8
        for (int k = 0; k < 64; ++k) ss = fmaf(HS[ln][k], HS[ln][k], ss);
        float my = sqrtf(ss);
        int S = 0;   // occurrences of tokens ranked strictly before ln
        for (int t2 = 0; t2 < 64; ++t2) {
            float s2 = __shfl(my, t2);
            int   h2 = __shfl(h, t2);
            bool before = (s2 > my) || (s2 == my && t2 < ln);
            if (before) S += h2;
        }
        int rem = 64 - S;
        rem = rem < 0 ? 0 : rem;
        cnt_i = h < rem ? h : rem;
    } else if (wv == 1) {
        int tl = tlast_s;
        float acc = bias;
        #pragma unroll
        for (int k = 0; k < 64; ++k)
            acc = fmaf(HS[tl][k], wcol[k], acc);    // HS row broadcast
        qv[ln] = acc;
    }
    __syncthreads();

    // ---- Phase 2: wave0: logits -> softmax(w/ mult) -> ctx -> out ----
    if (wv == 0) {
        float acc = 0.f;
        #pragma unroll 8
        for (int k = 0; k < 64; ++k)
            acc = fmaf(qv[k], HS[ln][k], acc);
        float logit = acc * 0.125f;                 // / sqrt(64)
        float lm = (cnt_i > 0) ? logit : -1e30f;
        #pragma unroll
        for (int off = 1; off < 64; off <<= 1) lm = fmaxf(lm, __shfl_xor(lm, off));
        float wvv = (cnt_i > 0) ? (float)cnt_i * __expf(logit - lm) : 0.f;
        float z = wvv;
        #pragma unroll
        for (int off = 1; off < 64; off <<= 1) z += __shfl_xor(z, off);
        float w_reg = wvv / z;                      // lane t holds weight_t

        float cacc = 0.f;                           // ctx[ln]
        #pragma unroll 8
        for (int t2 = 0; t2 < 64; ++t2)
            cacc = fmaf(__shfl(w_reg, t2), HS[t2][ln], cacc);

        float oacc = bias;                          // out[ln]
        #pragma unroll
        for (int k = 0; k < 64; ++k)
            oacc = fmaf(__shfl(cacc, k), wcol[k], oacc);
        out[b * 64 + ln] = oacc;
    }
}

extern "C" void kernel_launch(void* const* d_in, const int* in_sizes, int n_in,
                              void* d_out, int out_size, void* d_ws, size_t ws_size,
                              hipStream_t stream) {
    const int*   seq   = (const int*)d_in[0];
    const float* embed = (const float*)d_in[1];
    const float* W1    = (const float*)d_in[2];
    const float* b1    = (const float*)d_in[3];
    const float* W2    = (const float*)d_in[4];
    const float* b2    = (const float*)d_in[5];
    const float* gamma = (const float*)d_in[6];
    const float* beta  = (const float*)d_in[7];
    const float* Wq    = (const float*)d_in[8];
    const float* bq    = (const float*)d_in[9];
    const float* Wo    = (const float*)d_in[10];
    const float* bo    = (const float*)d_in[11];
    float* out = (float*)d_out;
    (void)in_sizes; (void)n_in; (void)out_size; (void)d_ws; (void)ws_size;

    slot_single<<<256, 512, 0, stream>>>(seq, embed, W1, b1, W2, b2,
                                         gamma, beta, Wq, bq, Wo, bo, out);
}

// Round 8
// 22.311 us; speedup vs baseline: 2.2548x; 1.1476x over previous
//
#include <hip/hip_runtime.h>
#include <math.h>

#define EPS 1e-5f

// Single plain launch, 256 blocks x 1024 threads (16 waves), 1 block/CU.
// Every block redundantly rebuilds the 64-token table (net up to `hs` depends
// only on token id; VALU floor ~3.4us, wall-clock free at grid==CU count),
// histograms its own batch row, and runs the attention epilogue.
// Key layout: lane = token. Weights are WAVE-UNIFORM (readfirstlane'd column
// offset) and read straight from global -> SMEM s_load path, zero LDS-pipe
// cost. Activations row-major in LDS with stride%32==4 padding (2-way bank
// aliasing = free), read as float4.
__global__ __launch_bounds__(1024) void slot_v2(
    const int* __restrict__ seq,
    const float* __restrict__ embed,
    const float* __restrict__ W1, const float* __restrict__ b1,
    const float* __restrict__ W2, const float* __restrict__ b2,
    const float* __restrict__ gamma, const float* __restrict__ beta,
    const float* __restrict__ Wq, const float* __restrict__ bq,
    const float* __restrict__ Wo, const float* __restrict__ bo,
    float* __restrict__ out)
{
    __shared__ float E[64][68];     // embed rows; stride 68 (bank step 4, 2-way)
    __shared__ float U[64][132];    // relu(E@W1+b1); stride 132 (bank step 4)
    __shared__ float HS[64][68];    // layernormed table
    __shared__ float Pp[16][64];    // per-wave LN partials
    __shared__ float qv[64];
    __shared__ int   hist[16][64];
    __shared__ int   tlast_s;

    const int tid = threadIdx.x;
    const int wv  = tid >> 6;       // 0..15
    const int ln  = tid & 63;       // lane = token
    const int b   = blockIdx.x;
    const int* row = seq + b * 4096;

    hist[wv][ln] = 0;

    // One int4 of the sequence per thread (4096 ints exactly).
    int4 sv = reinterpret_cast<const int4*>(row)[tid];

    // Stage embed row-major (16KB, coalesced; 2-way write aliasing = free).
    {
        float4 v = reinterpret_cast<const float4*>(embed)[tid];
        int t = tid >> 4, j0 = (tid & 15) << 2;
        *reinterpret_cast<float4*>(&E[t][j0]) = v;
    }
    __syncthreads();

    // Histogram own row (positions 0..4092; 4093/4094 dropped, 4095 = tlast).
    atomicAdd(&hist[wv][sv.x], 1);
    if (tid != 1023) {
        atomicAdd(&hist[wv][sv.y], 1);
        atomicAdd(&hist[wv][sv.z], 1);
        atomicAdd(&hist[wv][sv.w], 1);
    } else {
        tlast_s = sv.w;
    }

    // Wave-uniform column offsets (SGPR -> weight loads become s_load).
    const int wvu = __builtin_amdgcn_readfirstlane(wv);

    // ---- U = relu(E@W1 + b1): lane=token, wave owns cols 8*wvu..8*wvu+7 ----
    {
        const int c0 = wvu << 3;
        const float* __restrict__ w1c = W1 + c0;
        float acc[8];
        #pragma unroll
        for (int i = 0; i < 8; ++i) acc[i] = b1[c0 + i];     // uniform
        #pragma unroll 4
        for (int k = 0; k < 64; k += 4) {
            float4 ev = *reinterpret_cast<const float4*>(&E[ln][k]);
            #pragma unroll
            for (int kk = 0; kk < 4; ++kk) {
                const float* wr = w1c + (k + kk) * 128;      // uniform addr
                float e = (kk == 0) ? ev.x : (kk == 1) ? ev.y
                        : (kk == 2) ? ev.z : ev.w;
                #pragma unroll
                for (int i = 0; i < 8; ++i)
                    acc[i] = fmaf(e, wr[i], acc[i]);
            }
        }
        float4 ua = make_float4(fmaxf(acc[0],0.f), fmaxf(acc[1],0.f),
                                fmaxf(acc[2],0.f), fmaxf(acc[3],0.f));
        float4 ub = make_float4(fmaxf(acc[4],0.f), fmaxf(acc[5],0.f),
                                fmaxf(acc[6],0.f), fmaxf(acc[7],0.f));
        *reinterpret_cast<float4*>(&U[ln][c0])     = ua;
        *reinterpret_cast<float4*>(&U[ln][c0 + 4]) = ub;
    }
    __syncthreads();

    // ---- H = E + U@W2 + b2: lane=token, wave owns cols 4*wvu..4*wvu+3 ----
    float hacc[4];
    const int j0 = wvu << 2;
    {
        const float* __restrict__ w2c = W2 + j0;
        #pragma unroll
        for (int i = 0; i < 4; ++i) hacc[i] = b2[j0 + i];    // uniform
        #pragma unroll 4
        for (int k = 0; k < 128; k += 4) {
            float4 uv = *reinterpret_cast<const float4*>(&U[ln][k]);
            #pragma unroll
            for (int kk = 0; kk < 4; ++kk) {
                const float* wr = w2c + (k + kk) * 64;       // uniform addr
                float u = (kk == 0) ? uv.x : (kk == 1) ? uv.y
                        : (kk == 2) ? uv.z : uv.w;
                #pragma unroll
                for (int i = 0; i < 4; ++i)
                    hacc[i] = fmaf(u, wr[i], hacc[i]);
            }
        }
        float4 ee = *reinterpret_cast<const float4*>(&E[ln][j0]);
        hacc[0] += ee.x; hacc[1] += ee.y; hacc[2] += ee.z; hacc[3] += ee.w;
        Pp[wv][ln] = hacc[0] + hacc[1] + hacc[2] + hacc[3];
    }
    __syncthreads();

    float mu, v4;
    {
        float s = 0.f;
        #pragma unroll
        for (int w = 0; w < 16; ++w) s += Pp[w][ln];         // lane-idx, CF
        mu = s * (1.f / 64.f);
        v4 = 0.f;
        #pragma unroll
        for (int i = 0; i < 4; ++i) { float d = hacc[i] - mu; v4 = fmaf(d, d, v4); }
    }
    __syncthreads();   // all Pp sum-reads done before overwrite
    Pp[wv][ln] = v4;
    __syncthreads();
    {
        float v = 0.f;
        #pragma unroll
        for (int w = 0; w < 16; ++w) v += Pp[w][ln];
        float rstd = rsqrtf(v * (1.f / 64.f) + EPS);
        float4 gg = *reinterpret_cast<const float4*>(&gamma[j0]);  // uniform
        float4 be = *reinterpret_cast<const float4*>(&beta[j0]);
        float4 hs;
        hs.x = (hacc[0] - mu) * rstd * gg.x + be.x;
        hs.y = (hacc[1] - mu) * rstd * gg.y + be.y;
        hs.z = (hacc[2] - mu) * rstd * gg.z + be.z;
        hs.w = (hacc[3] - mu) * rstd * gg.w + be.w;
        *reinterpret_cast<float4*>(&HS[ln][j0]) = hs;
    }
    __syncthreads();   // HS + hist complete

    // ---- Phase 1: wave0 -> scores+counts; wave1 -> q = HS[tlast]@Wq+bq ----
    int cnt_i = 0;
    if (wv == 0) {
        int h = 0;
        #pragma unroll
        for (int w = 0; w < 16; ++w) h += hist[w][ln];
        float ss = 0.f;
        #pragma unroll
        for (int k = 0; k < 64; k += 4) {
            float4 x = *reinterpret_cast<const float4*>(&HS[ln][k]);
            ss = fmaf(x.x, x.x, ss); ss = fmaf(x.y, x.y, ss);
            ss = fmaf(x.z, x.z, ss); ss = fmaf(x.w, x.w, ss);
        }
        float my = sqrtf(ss);
        int S = 0;   // occurrences of tokens ranked strictly before ln
        for (int t2 = 0; t2 < 64; ++t2) {
            float s2 = __shfl(my, t2);
            int   h2 = __shfl(h, t2);
            bool before = (s2 > my) || (s2 == my && t2 < ln);
            if (before) S += h2;
        }
        int rem = 64 - S;
        rem = rem < 0 ? 0 : rem;
        cnt_i = h < rem ? h : rem;
    } else if (wv == 1) {
        int tl = tlast_s;
        float acc = bq[ln];
        #pragma unroll
        for (int k = 0; k < 64; ++k)
            acc = fmaf(HS[tl][k], Wq[k * 64 + ln], acc);  // bcast x coalesced
        qv[ln] = acc;
    }
    __syncthreads();

    // ---- Phase 2: wave0: logits -> softmax(w/ mult) -> ctx -> out ----
    if (wv == 0) {
        float acc = 0.f;
        #pragma unroll 8
        for (int k = 0; k < 64; ++k)
            acc = fmaf(qv[k], HS[ln][k], acc);
        float logit = acc * 0.125f;                 // / sqrt(64)
        float lm = (cnt_i > 0) ? logit : -1e30f;
        #pragma unroll
        for (int off = 1; off < 64; off <<= 1) lm = fmaxf(lm, __shfl_xor(lm, off));
        float wvv = (cnt_i > 0) ? (float)cnt_i * __expf(logit - lm) : 0.f;
        float z = wvv;
        #pragma unroll
        for (int off = 1; off < 64; off <<= 1) z += __shfl_xor(z, off);
        float w_reg = wvv / z;                      // lane t holds weight_t

        float cacc = 0.f;                           // ctx[ln]
        #pragma unroll 8
        for (int t2 = 0; t2 < 64; ++t2)
            cacc = fmaf(__shfl(w_reg, t2), HS[t2][ln], cacc);

        float oacc = bo[ln];                        // out[ln]
        #pragma unroll
        for (int k = 0; k < 64; ++k)
            oacc = fmaf(__shfl(cacc, k), Wo[k * 64 + ln], oacc);
        out[b * 64 + ln] = oacc;
    }
}

extern "C" void kernel_launch(void* const* d_in, const int* in_sizes, int n_in,
                              void* d_out, int out_size, void* d_ws, size_t ws_size,
                              hipStream_t stream) {
    const int*   seq   = (const int*)d_in[0];
    const float* embed = (const float*)d_in[1];
    const float* W1    = (const float*)d_in[2];
    const float* b1    = (const float*)d_in[3];
    const float* W2    = (const float*)d_in[4];
    const float* b2    = (const float*)d_in[5];
    const float* gamma = (const float*)d_in[6];
    const float* beta  = (const float*)d_in[7];
    const float* Wq    = (const float*)d_in[8];
    const float* bq    = (const float*)d_in[9];
    const float* Wo    = (const float*)d_in[10];
    const float* bo    = (const float*)d_in[11];
    float* out = (float*)d_out;
    (void)in_sizes; (void)n_in; (void)out_size; (void)d_ws; (void)ws_size;

    slot_v2<<<256, 1024, 0, stream>>>(seq, embed, W1, b1, W2, b2,
                                      gamma, beta, Wq, bq, Wo, bo, out);
}

// Round 9
// 19.822 us; speedup vs baseline: 2.5379x; 1.1256x over previous
//
#include <hip/hip_runtime.h>
#include <math.h>

#define EPS 1e-5f

// ws layout (floats): [0,4096) HS table row-major; [4096,4160) gate scores.
// ws ints (at float offset 4160): [0,16384) per-row hist; [16384,16640) tlast.

// ---- Kernel A: blocks 0..7 = table (1 wave per token, no LDS/barriers);
//      blocks 8..263 = per-row histogram (512 thr, 8 sub-hists). ----
__global__ __launch_bounds__(512) void table_hist(
    const int* __restrict__ seq,
    const float* __restrict__ embed,
    const float* __restrict__ W1, const float* __restrict__ b1,
    const float* __restrict__ W2, const float* __restrict__ b2,
    const float* __restrict__ gamma, const float* __restrict__ beta,
    float* __restrict__ wsf, int* __restrict__ wsi_hist,
    int* __restrict__ wsi_tlast)
{
    const int tid = threadIdx.x;
    const int wv  = tid >> 6;
    const int ln  = tid & 63;

    if (blockIdx.x < 8) {
        // -------- table: token t, one wave, lane = column --------
        const int t = blockIdx.x * 8 + wv;
        float e = embed[t * 64 + ln];

        // U = relu(e@W1+b1): lane owns cols ln and ln+64; 2-way split chains.
        float a0p0 = b1[ln],      a0p1 = 0.f;
        float a1p0 = b1[64 + ln], a1p1 = 0.f;
        #pragma unroll 8
        for (int j = 0; j < 64; j += 2) {
            float ej0 = __shfl(e, j);
            float ej1 = __shfl(e, j + 1);
            a0p0 = fmaf(ej0, W1[j * 128 + ln],            a0p0);
            a1p0 = fmaf(ej0, W1[j * 128 + 64 + ln],       a1p0);
            a0p1 = fmaf(ej1, (W1 + 128)[j * 128 + ln],      a0p1);
            a1p1 = fmaf(ej1, (W1 + 128)[j * 128 + 64 + ln], a1p1);
        }
        float u0 = fmaxf(a0p0 + a0p1, 0.f);
        float u1 = fmaxf(a1p0 + a1p1, 0.f);

        // H = e + U@W2 + b2: lane owns col ln; 2-way split chains.
        float hp0 = e + b2[ln], hp1 = 0.f;
        #pragma unroll 8
        for (int k = 0; k < 64; k += 2) {
            hp0 = fmaf(__shfl(u0, k),     W2[k * 64 + ln],       hp0);
            hp1 = fmaf(__shfl(u0, k + 1), W2[(k + 1) * 64 + ln], hp1);
        }
        #pragma unroll 8
        for (int k = 0; k < 64; k += 2) {
            hp0 = fmaf(__shfl(u1, k),     W2[(64 + k) * 64 + ln],     hp0);
            hp1 = fmaf(__shfl(u1, k + 1), W2[(64 + k + 1) * 64 + ln], hp1);
        }
        float h = hp0 + hp1;

        // LN + gamma/beta + gate norm, in-wave reductions.
        float s = h;
        #pragma unroll
        for (int off = 1; off < 64; off <<= 1) s += __shfl_xor(s, off);
        float mu = s * (1.f / 64.f);
        float d = h - mu;
        float v = d * d;
        #pragma unroll
        for (int off = 1; off < 64; off <<= 1) v += __shfl_xor(v, off);
        float rstd = rsqrtf(v * (1.f / 64.f) + EPS);
        float hs = d * rstd * gamma[ln] + beta[ln];
        wsf[t * 64 + ln] = hs;
        float ss = hs * hs;
        #pragma unroll
        for (int off = 1; off < 64; off <<= 1) ss += __shfl_xor(ss, off);
        if (ln == 0) wsf[4096 + t] = sqrtf(ss);
    } else {
        // -------- histogram of row b (positions 0..4092) --------
        __shared__ int hist[8][64];
        const int b = blockIdx.x - 8;
        const int* row = seq + b * 4096;

        hist[wv][ln] = 0;
        int4 v0 = reinterpret_cast<const int4*>(row)[tid];         // idx 0..511
        int4 v1 = reinterpret_cast<const int4*>(row)[tid + 512];   // idx 512..1023
        __syncthreads();

        atomicAdd(&hist[wv][v0.x], 1); atomicAdd(&hist[wv][v0.y], 1);
        atomicAdd(&hist[wv][v0.z], 1); atomicAdd(&hist[wv][v0.w], 1);
        atomicAdd(&hist[wv][v1.x], 1);                 // pos 4092 included
        if (tid != 511) {
            atomicAdd(&hist[wv][v1.y], 1);
            atomicAdd(&hist[wv][v1.z], 1);
            atomicAdd(&hist[wv][v1.w], 1);
        } else {
            wsi_tlast[b] = v1.w;                       // pos 4095
        }
        __syncthreads();

        if (tid < 64) {
            int hsum = 0;
            #pragma unroll
            for (int w = 0; w < 8; ++w) hsum += hist[w][tid];
            wsi_hist[b * 64 + tid] = hsum;
        }
    }
}

// ---- Kernel B: tiny per-row epilogue (verbatim R4, proven) ----
__global__ __launch_bounds__(256) void slot_epilogue(
    const float* __restrict__ Wq, const float* __restrict__ bq,
    const float* __restrict__ Wo, const float* __restrict__ bo,
    const float* __restrict__ wsf, const int* __restrict__ wsi_hist,
    const int* __restrict__ wsi_tlast,
    float* __restrict__ out)
{
    __shared__ float HS[64][65];
    __shared__ float qv[64];

    const int tid = threadIdx.x;
    const int wv  = tid >> 6;
    const int ln  = tid & 63;
    const int b   = blockIdx.x;

    float wcol[64];
    float bias = 0.f, sc_r = 0.f;
    int h = 0, tl = 0;
    if (wv == 0) {
        #pragma unroll
        for (int k = 0; k < 64; ++k) wcol[k] = Wo[k * 64 + ln];
        bias = bo[ln];
        sc_r = wsf[4096 + ln];
        h    = wsi_hist[b * 64 + ln];
    } else if (wv == 1) {
        #pragma unroll
        for (int k = 0; k < 64; ++k) wcol[k] = Wq[k * 64 + ln];
        bias = bq[ln];
        tl   = wsi_tlast[b];
    }

    #pragma unroll
    for (int i = 0; i < 4; ++i) {
        int idx4 = tid + 256 * i;
        float4 v = reinterpret_cast<const float4*>(wsf)[idx4];
        int t = idx4 >> 4, j0 = (idx4 & 15) << 2;
        HS[t][j0] = v.x; HS[t][j0+1] = v.y; HS[t][j0+2] = v.z; HS[t][j0+3] = v.w;
    }
    __syncthreads();

    int cnt_i = 0;
    if (wv == 0) {
        float my = sc_r;
        int S = 0;
        for (int t2 = 0; t2 < 64; ++t2) {
            float s2 = __shfl(sc_r, t2);
            int   h2 = __shfl(h, t2);
            bool before = (s2 > my) || (s2 == my && t2 < ln);
            if (before) S += h2;
        }
        int rem = 64 - S;
        rem = rem < 0 ? 0 : rem;
        cnt_i = h < rem ? h : rem;
    } else if (wv == 1) {
        float acc = bias;
        #pragma unroll
        for (int k = 0; k < 64; ++k)
            acc = fmaf(HS[tl][k], wcol[k], acc);
        qv[ln] = acc;
    }
    __syncthreads();

    if (wv == 0) {
        float acc = 0.f;
        #pragma unroll 8
        for (int k = 0; k < 64; ++k)
            acc = fmaf(qv[k], HS[ln][k], acc);
        float logit = acc * 0.125f;
        float lm = (cnt_i > 0) ? logit : -1e30f;
        #pragma unroll
        for (int off = 1; off < 64; off <<= 1) lm = fmaxf(lm, __shfl_xor(lm, off));
        float wvv = (cnt_i > 0) ? (float)cnt_i * __expf(logit - lm) : 0.f;
        float z = wvv;
        #pragma unroll
        for (int off = 1; off < 64; off <<= 1) z += __shfl_xor(z, off);
        float w_reg = wvv / z;

        float cacc = 0.f;
        #pragma unroll 8
        for (int t2 = 0; t2 < 64; ++t2)
            cacc = fmaf(__shfl(w_reg, t2), HS[t2][ln], cacc);

        float oacc = bias;
        #pragma unroll
        for (int k = 0; k < 64; ++k)
            oacc = fmaf(__shfl(cacc, k), wcol[k], oacc);
        out[b * 64 + ln] = oacc;
    }
}

extern "C" void kernel_launch(void* const* d_in, const int* in_sizes, int n_in,
                              void* d_out, int out_size, void* d_ws, size_t ws_size,
                              hipStream_t stream) {
    const int*   seq   = (const int*)d_in[0];
    const float* embed = (const float*)d_in[1];
    const float* W1    = (const float*)d_in[2];
    const float* b1    = (const float*)d_in[3];
    const float* W2    = (const float*)d_in[4];
    const float* b2    = (const float*)d_in[5];
    const float* gamma = (const float*)d_in[6];
    const float* beta  = (const float*)d_in[7];
    const float* Wq    = (const float*)d_in[8];
    const float* bq    = (const float*)d_in[9];
    const float* Wo    = (const float*)d_in[10];
    const float* bo    = (const float*)d_in[11];
    float* out = (float*)d_out;
    float* wsf = (float*)d_ws;
    int*   wsi_hist  = (int*)(wsf + 4160);
    int*   wsi_tlast = wsi_hist + 256 * 64;
    (void)in_sizes; (void)n_in; (void)out_size; (void)ws_size;

    table_hist<<<264, 512, 0, stream>>>(seq, embed, W1, b1, W2, b2,
                                        gamma, beta, wsf, wsi_hist, wsi_tlast);
    slot_epilogue<<<256, 256, 0, stream>>>(Wq, bq, Wo, bo, wsf, wsi_hist,
                                           wsi_tlast, out);
}

// Round 10
// 18.824 us; speedup vs baseline: 2.6725x; 1.0530x over previous
//
#include <hip/hip_runtime.h>
#include <math.h>

#define EPS 1e-5f

// ws layout (floats): [0,4096) HS table row-major; [4096,4160) gate scores.
// ws ints (at float offset 4160): [0,16384) per-row hist; [16384,16640) tlast.

// ---- Kernel A: blocks 0..15 = table (wave-per-token, no LDS, no barriers);
//      blocks 16..271 = per-row histogram (256 thr, 16 atomics/thread). ----
__global__ __launch_bounds__(256) void table_hist(
    const int* __restrict__ seq,
    const float* __restrict__ embed,
    const float* __restrict__ W1, const float* __restrict__ b1,
    const float* __restrict__ W2, const float* __restrict__ b2,
    const float* __restrict__ gamma, const float* __restrict__ beta,
    float* __restrict__ wsf, int* __restrict__ wsi_hist,
    int* __restrict__ wsi_tlast)
{
    const int tid = threadIdx.x;
    const int wv  = tid >> 6;
    const int ln  = tid & 63;

    if (blockIdx.x < 16) {
        // -------- table: token t = 4*block + wave; lane = column --------
        const int t = blockIdx.x * 4 + wv;
        float e = embed[t * 64 + ln];

        // U = relu(e@W1+b1): lane owns cols ln, ln+64; 2 split chains each.
        // __shfl with unrolled-constant lane -> v_readlane (SGPR broadcast).
        float a0 = b1[ln],      a0b = 0.f;
        float a1 = b1[64 + ln], a1b = 0.f;
        #pragma unroll
        for (int j = 0; j < 64; j += 2) {
            float ej0 = __shfl(e, j);
            float ej1 = __shfl(e, j + 1);
            a0  = fmaf(ej0, W1[j * 128 + ln],            a0);
            a1  = fmaf(ej0, W1[j * 128 + 64 + ln],       a1);
            a0b = fmaf(ej1, W1[(j + 1) * 128 + ln],      a0b);
            a1b = fmaf(ej1, W1[(j + 1) * 128 + 64 + ln], a1b);
        }
        float u0 = fmaxf(a0 + a0b, 0.f);
        float u1 = fmaxf(a1 + a1b, 0.f);

        // H = e + U@W2 + b2: lane owns col ln; 2 split chains.
        float hp0 = e + b2[ln], hp1 = 0.f;
        #pragma unroll
        for (int k = 0; k < 64; k += 2) {
            hp0 = fmaf(__shfl(u0, k),     W2[k * 64 + ln],       hp0);
            hp1 = fmaf(__shfl(u0, k + 1), W2[(k + 1) * 64 + ln], hp1);
        }
        #pragma unroll
        for (int k = 0; k < 64; k += 2) {
            hp0 = fmaf(__shfl(u1, k),     W2[(64 + k) * 64 + ln], hp0);
            hp1 = fmaf(__shfl(u1, k + 1), W2[(65 + k) * 64 + ln], hp1);
        }
        float h = hp0 + hp1;

        // LN + gamma/beta + gate norm, in-wave reductions.
        float s = h;
        #pragma unroll
        for (int off = 1; off < 64; off <<= 1) s += __shfl_xor(s, off);
        float mu = s * (1.f / 64.f);
        float d = h - mu;
        float v = d * d;
        #pragma unroll
        for (int off = 1; off < 64; off <<= 1) v += __shfl_xor(v, off);
        float rstd = rsqrtf(v * (1.f / 64.f) + EPS);
        float hs = d * rstd * gamma[ln] + beta[ln];
        wsf[t * 64 + ln] = hs;
        float ss = hs * hs;
        #pragma unroll
        for (int off = 1; off < 64; off <<= 1) ss += __shfl_xor(ss, off);
        if (ln == 0) wsf[4096 + t] = sqrtf(ss);
    } else {
        // -------- histogram of row b (positions 0..4092) --------
        __shared__ int hist[4][64];
        const int b = blockIdx.x - 16;
        const int* row = seq + b * 4096;

        hist[wv][ln] = 0;
        __syncthreads();

        #pragma unroll
        for (int i = 0; i < 4; ++i) {
            int idx = tid + 256 * i;
            if (idx < 1023) {
                int4 v = reinterpret_cast<const int4*>(row)[idx];
                atomicAdd(&hist[wv][v.x], 1);
                atomicAdd(&hist[wv][v.y], 1);
                atomicAdd(&hist[wv][v.z], 1);
                atomicAdd(&hist[wv][v.w], 1);
            }
        }
        if (tid == 0) {
            atomicAdd(&hist[0][row[4092]], 1);
            wsi_tlast[b] = row[4095];
        }
        __syncthreads();

        if (tid < 64)
            wsi_hist[b * 64 + tid] =
                hist[0][tid] + hist[1][tid] + hist[2][tid] + hist[3][tid];
    }
}

// ---- Kernel B: per-row epilogue, single barrier ----
// Rank (wave0) and q (wave1) are LDS-free and overlap the HS staging done
// by all 4 waves; one barrier; then wave0 runs logits->softmax->ctx->out.
__global__ __launch_bounds__(256) void slot_epilogue(
    const float* __restrict__ Wq, const float* __restrict__ bq,
    const float* __restrict__ Wo, const float* __restrict__ bo,
    const float* __restrict__ wsf, const int* __restrict__ wsi_hist,
    const int* __restrict__ wsi_tlast,
    float* __restrict__ out)
{
    __shared__ float HS[64][65];    // pad 65: row+col reads conflict-free
    __shared__ float qv[64];

    const int tid = threadIdx.x;
    const int wv  = tid >> 6;
    const int ln  = tid & 63;
    const int b   = blockIdx.x;

    // Entry loads. wave0: Wo col + bo + score + hist count.
    //              wave1: Wq col + bq + tlast + HS[tlast] row (global).
    float wcol[64];
    float bias = 0.f, sc_r = 0.f, hsq = 0.f;
    int h = 0;
    if (wv == 0) {
        #pragma unroll
        for (int k = 0; k < 64; ++k) wcol[k] = Wo[k * 64 + ln];
        bias = bo[ln];
        sc_r = wsf[4096 + ln];
        h    = wsi_hist[b * 64 + ln];
    } else if (wv == 1) {
        #pragma unroll
        for (int k = 0; k < 64; ++k) wcol[k] = Wq[k * 64 + ln];
        bias = bq[ln];
        int tl = wsi_tlast[b];
        hsq  = wsf[tl * 64 + ln];          // one coalesced row load
    }

    // Stage HS table (16KB, L2-resident) — all 4 waves.
    #pragma unroll
    for (int i = 0; i < 4; ++i) {
        int idx4 = tid + 256 * i;
        float4 v = reinterpret_cast<const float4*>(wsf)[idx4];
        int t = idx4 >> 4, j0 = (idx4 & 15) << 2;
        HS[t][j0] = v.x; HS[t][j0+1] = v.y; HS[t][j0+2] = v.z; HS[t][j0+3] = v.w;
    }

    // Phase 1 (LDS-free): wave0 -> slot counts; wave1 -> q via readlane bcast.
    int cnt_i = 0;
    if (wv == 0) {
        float my = sc_r;
        int S = 0;   // occurrences of tokens ranked strictly before ln
        #pragma unroll
        for (int t2 = 0; t2 < 64; ++t2) {
            float s2 = __shfl(sc_r, t2);
            int   h2 = __shfl(h, t2);
            bool before = (s2 > my) || (s2 == my && t2 < ln);
            if (before) S += h2;
        }
        int rem = 64 - S;
        rem = rem < 0 ? 0 : rem;
        cnt_i = h < rem ? h : rem;
    } else if (wv == 1) {
        float acc = bias;
        #pragma unroll
        for (int k = 0; k < 64; ++k)
            acc = fmaf(__shfl(hsq, k), wcol[k], acc);
        qv[ln] = acc;
    }
    __syncthreads();   // HS staged + qv written

    // Phase 2: wave0: logits -> softmax(w/ multiplicity) -> ctx -> out.
    if (wv == 0) {
        float acc = 0.f;
        #pragma unroll 8
        for (int k = 0; k < 64; ++k)
            acc = fmaf(qv[k], HS[ln][k], acc);
        float logit = acc * 0.125f;                 // / sqrt(64)
        float lm = (cnt_i > 0) ? logit : -1e30f;
        #pragma unroll
        for (int off = 1; off < 64; off <<= 1) lm = fmaxf(lm, __shfl_xor(lm, off));
        float wvv = (cnt_i > 0) ? (float)cnt_i * __expf(logit - lm) : 0.f;
        float z = wvv;
        #pragma unroll
        for (int off = 1; off < 64; off <<= 1) z += __shfl_xor(z, off);
        float w_reg = wvv / z;                      // lane t holds weight_t

        float cacc = 0.f;                           // ctx[ln]
        #pragma unroll 8
        for (int t2 = 0; t2 < 64; ++t2)
            cacc = fmaf(__shfl(w_reg, t2), HS[t2][ln], cacc);

        float oacc = bias;                          // out[ln]
        #pragma unroll
        for (int k = 0; k < 64; ++k)
            oacc = fmaf(__shfl(cacc, k), wcol[k], oacc);
        out[b * 64 + ln] = oacc;
    }
}

extern "C" void kernel_launch(void* const* d_in, const int* in_sizes, int n_in,
                              void* d_out, int out_size, void* d_ws, size_t ws_size,
                              hipStream_t stream) {
    const int*   seq   = (const int*)d_in[0];
    const float* embed = (const float*)d_in[1];
    const float* W1    = (const float*)d_in[2];
    const float* b1    = (const float*)d_in[3];
    const float* W2    = (const float*)d_in[4];
    const float* b2    = (const float*)d_in[5];
    const float* gamma = (const float*)d_in[6];
    const float* beta  = (const float*)d_in[7];
    const float* Wq    = (const float*)d_in[8];
    const float* bq    = (const float*)d_in[9];
    const float* Wo    = (const float*)d_in[10];
    const float* bo    = (const float*)d_in[11];
    float* out = (float*)d_out;
    float* wsf = (float*)d_ws;
    int*   wsi_hist  = (int*)(wsf + 4160);
    int*   wsi_tlast = wsi_hist + 256 * 64;
    (void)in_sizes; (void)n_in; (void)out_size; (void)ws_size;

    table_hist<<<272, 256, 0, stream>>>(seq, embed, W1, b1, W2, b2,
                                        gamma, beta, wsf, wsi_hist, wsi_tlast);
    slot_epilogue<<<256, 256, 0, stream>>>(Wq, bq, Wo, bo, wsf, wsi_hist,
                                           wsi_tlast, out);
}

// Round 11
// 16.936 us; speedup vs baseline: 2.9703x; 1.1115x over previous
//
#include <hip/hip_runtime.h>
#include <math.h>

#define EPS 1e-5f

// ws layout (floats): [0,4096) HS table row-major; [4096,4160) gate scores.
// ws ints (at float offset 4160): [0,32768) per-row half-hists (256 rows x
// 2 halves x 64); then [32768,33024) tlast.

// ---- Kernel A: blocks 0..63 = table (R4-proven LDS-staged, 1 token/block);
//      blocks 64..575 = half-row histograms (2 blocks per batch row). ----
__global__ __launch_bounds__(256) void table_hist(
    const int* __restrict__ seq,
    const float* __restrict__ embed,
    const float* __restrict__ W1, const float* __restrict__ b1,
    const float* __restrict__ W2, const float* __restrict__ b2,
    const float* __restrict__ gamma, const float* __restrict__ beta,
    float* __restrict__ wsf, int* __restrict__ wsi_hist,
    int* __restrict__ wsi_tlast)
{
    const int tid = threadIdx.x;

    if (blockIdx.x < 64) {
        // ---------- build one token's table row (R4 verbatim) ----------
        __shared__ float W1s[64][128];
        __shared__ float W2s[128][64];
        __shared__ float e[64];
        __shared__ float Up[2][128];
        __shared__ float U[128];
        __shared__ float Hp[4][64];

        const int t = blockIdx.x;

        #pragma unroll
        for (int i = 0; i < 8; ++i) {
            reinterpret_cast<float4*>(&W1s[0][0])[tid + 256 * i] =
                reinterpret_cast<const float4*>(W1)[tid + 256 * i];
            reinterpret_cast<float4*>(&W2s[0][0])[tid + 256 * i] =
                reinterpret_cast<const float4*>(W2)[tid + 256 * i];
        }
        if (tid < 64) e[tid] = embed[t * 64 + tid];
        __syncthreads();

        {   // U = relu(e@W1 + b1), split-K halves
            int j = tid & 127, h = tid >> 7;
            int k0 = h << 5;
            float acc = 0.f;
            #pragma unroll 8
            for (int k = 0; k < 32; ++k)
                acc = fmaf(e[k0 + k], W1s[k0 + k][j], acc);
            Up[h][j] = acc;
        }
        __syncthreads();
        if (tid < 128) U[tid] = fmaxf(b1[tid] + Up[0][tid] + Up[1][tid], 0.f);
        __syncthreads();

        {   // H = e + U@W2 + b2, split-K quarters
            int j = tid & 63, qd = tid >> 6;
            int k0 = qd << 5;
            float acc = 0.f;
            #pragma unroll 8
            for (int k = 0; k < 32; ++k)
                acc = fmaf(U[k0 + k], W2s[k0 + k][j], acc);
            Hp[qd][j] = acc;
        }
        __syncthreads();

        if (tid < 64) {   // LN + gamma/beta + gate norm
            float h = e[tid] + b2[tid] + Hp[0][tid] + Hp[1][tid] + Hp[2][tid] + Hp[3][tid];
            float s = h;
            #pragma unroll
            for (int off = 1; off < 64; off <<= 1) s += __shfl_xor(s, off);
            float mu = s * (1.f / 64.f);
            float d = h - mu;
            float v = d * d;
            #pragma unroll
            for (int off = 1; off < 64; off <<= 1) v += __shfl_xor(v, off);
            float rstd = rsqrtf(v * (1.f / 64.f) + EPS);
            float hs = d * rstd * gamma[tid] + beta[tid];
            wsf[t * 64 + tid] = hs;
            float ss = hs * hs;
            #pragma unroll
            for (int off = 1; off < 64; off <<= 1) ss += __shfl_xor(ss, off);
            if (tid == 0) wsf[4096 + t] = sqrtf(ss);
        }
    } else {
        // ---------- half-row histogram: 2 blocks per batch row ----------
        __shared__ int hist[4][64];
        const int idx  = blockIdx.x - 64;
        const int b    = idx >> 1;
        const int half = idx & 1;
        const int wv = tid >> 6, ln = tid & 63;
        const int* row = seq + b * 4096;

        hist[wv][ln] = 0;
        const int base = half * 512;                    // int4 index base
        int4 v0 = reinterpret_cast<const int4*>(row)[base + tid];
        int4 v1 = reinterpret_cast<const int4*>(row)[base + 256 + tid];
        __syncthreads();

        atomicAdd(&hist[wv][v0.x], 1); atomicAdd(&hist[wv][v0.y], 1);
        atomicAdd(&hist[wv][v0.z], 1); atomicAdd(&hist[wv][v0.w], 1);
        atomicAdd(&hist[wv][v1.x], 1);                  // pos 4092 included
        if (base + 256 + tid != 1023) {                 // drop 4093/4094
            atomicAdd(&hist[wv][v1.y], 1);
            atomicAdd(&hist[wv][v1.z], 1);
            atomicAdd(&hist[wv][v1.w], 1);
        } else {
            wsi_tlast[b] = v1.w;                        // pos 4095
        }
        __syncthreads();

        if (tid < 64)
            wsi_hist[b * 128 + half * 64 + tid] =
                hist[0][tid] + hist[1][tid] + hist[2][tid] + hist[3][tid];
    }
}

// ---- Kernel B: per-row epilogue (R4 verbatim, except 2 half-hist loads) ----
__global__ __launch_bounds__(256) void slot_epilogue(
    const float* __restrict__ Wq, const float* __restrict__ bq,
    const float* __restrict__ Wo, const float* __restrict__ bo,
    const float* __restrict__ wsf, const int* __restrict__ wsi_hist,
    const int* __restrict__ wsi_tlast,
    float* __restrict__ out)
{
    __shared__ float HS[64][65];    // pad 65: row+col access conflict-free
    __shared__ float qv[64];

    const int tid = threadIdx.x;
    const int wv  = tid >> 6;
    const int ln  = tid & 63;
    const int b   = blockIdx.x;

    // Register prefetch: wave0 = Wo column + bo + score + hist count;
    // wave1 = Wq column + bq + tlast. Fully unrolled -> VGPRs.
    float wcol[64];
    float bias = 0.f, sc_r = 0.f;
    int h = 0, tl = 0;
    if (wv == 0) {
        #pragma unroll
        for (int k = 0; k < 64; ++k) wcol[k] = Wo[k * 64 + ln];
        bias = bo[ln];
        sc_r = wsf[4096 + ln];
        h    = wsi_hist[b * 128 + ln] + wsi_hist[b * 128 + 64 + ln];
    } else if (wv == 1) {
        #pragma unroll
        for (int k = 0; k < 64; ++k) wcol[k] = Wq[k * 64 + ln];
        bias = bq[ln];
        tl   = wsi_tlast[b];
    }

    // Stage HS table (16KB, L2-resident) — all 4 waves.
    #pragma unroll
    for (int i = 0; i < 4; ++i) {
        int idx4 = tid + 256 * i;
        float4 v = reinterpret_cast<const float4*>(wsf)[idx4];
        int t = idx4 >> 4, j0 = (idx4 & 15) << 2;
        HS[t][j0] = v.x; HS[t][j0+1] = v.y; HS[t][j0+2] = v.z; HS[t][j0+3] = v.w;
    }
    __syncthreads();

    // Phase 1: wave0 -> slot counts; wave1 -> q = HS[tlast]@Wq + bq.
    int cnt_i = 0;
    if (wv == 0) {
        float my = sc_r;
        int S = 0;   // occurrences of tokens ranked strictly before ln
        for (int t2 = 0; t2 < 64; ++t2) {
            float s2 = __shfl(sc_r, t2);
            int   h2 = __shfl(h, t2);
            bool before = (s2 > my) || (s2 == my && t2 < ln);
            if (before) S += h2;
        }
        int rem = 64 - S;
        rem = rem < 0 ? 0 : rem;
        cnt_i = h < rem ? h : rem;
    } else if (wv == 1) {
        float acc = bias;
        #pragma unroll
        for (int k = 0; k < 64; ++k)
            acc = fmaf(HS[tl][k], wcol[k], acc);   // HS broadcast, wcol regs
        qv[ln] = acc;
    }
    __syncthreads();

    // Phase 2: wave0: logits -> softmax(w/ multiplicity) -> ctx -> out.
    if (wv == 0) {
        float acc = 0.f;
        #pragma unroll 8
        for (int k = 0; k < 64; ++k)
            acc = fmaf(qv[k], HS[ln][k], acc);
        float logit = acc * 0.125f;                // / sqrt(64)
        float lm = (cnt_i > 0) ? logit : -1e30f;
        #pragma unroll
        for (int off = 1; off < 64; off <<= 1) lm = fmaxf(lm, __shfl_xor(lm, off));
        float wvv = (cnt_i > 0) ? (float)cnt_i * __expf(logit - lm) : 0.f;
        float z = wvv;
        #pragma unroll
        for (int off = 1; off < 64; off <<= 1) z += __shfl_xor(z, off);
        float w_reg = wvv / z;                     // lane t holds weight_t

        float cacc = 0.f;                          // ctx[ln]
        #pragma unroll 8
        for (int t2 = 0; t2 < 64; ++t2)
            cacc = fmaf(__shfl(w_reg, t2), HS[t2][ln], cacc);

        float oacc = bias;                         // out[ln]
        #pragma unroll
        for (int k = 0; k < 64; ++k)
            oacc = fmaf(__shfl(cacc, k), wcol[k], oacc);
        out[b * 64 + ln] = oacc;
    }
}

extern "C" void kernel_launch(void* const* d_in, const int* in_sizes, int n_in,
                              void* d_out, int out_size, void* d_ws, size_t ws_size,
                              hipStream_t stream) {
    const int*   seq   = (const int*)d_in[0];
    const float* embed = (const float*)d_in[1];
    const float* W1    = (const float*)d_in[2];
    const float* b1    = (const float*)d_in[3];
    const float* W2    = (const float*)d_in[4];
    const float* b2    = (const float*)d_in[5];
    const float* gamma = (const float*)d_in[6];
    const float* beta  = (const float*)d_in[7];
    const float* Wq    = (const float*)d_in[8];
    const float* bq    = (const float*)d_in[9];
    const float* Wo    = (const float*)d_in[10];
    const float* bo    = (const float*)d_in[11];
    float* out = (float*)d_out;
    float* wsf = (float*)d_ws;
    int*   wsi_hist  = (int*)(wsf + 4160);
    int*   wsi_tlast = wsi_hist + 256 * 128;
    (void)in_sizes; (void)n_in; (void)out_size; (void)ws_size;

    table_hist<<<576, 256, 0, stream>>>(seq, embed, W1, b1, W2, b2,
                                        gamma, beta, wsf, wsi_hist, wsi_tlast);
    slot_epilogue<<<256, 256, 0, stream>>>(Wq, bq, Wo, bo, wsf, wsi_hist,
                                           wsi_tlast, out);
}